// Round 13
// baseline (1629.674 us; speedup 1.0000x reference)
//
#include <hip/hip_runtime.h>

static constexpr int TT = 512;   // sequence length
static constexpr int BB = 256;   // batch

typedef float v2f __attribute__((ext_vector_type(2)));

// LDS-only barrier: no vmcnt(0) drain, so global loads stay in flight across
// it (T4/T14 pattern). lgkmcnt(0) makes prior LDS writes visible.
#define BARRIER() do { \
    asm volatile("s_waitcnt lgkmcnt(0)" ::: "memory"); \
    __builtin_amdgcn_s_barrier(); \
    asm volatile("" ::: "memory"); \
  } while (0)

__device__ __forceinline__ float sigmoid_fast(float v) {
  const float e = __builtin_amdgcn_exp2f(v * -1.44269504088896340736f);
  return __builtin_amdgcn_rcpf(1.0f + e);
}
__device__ __forceinline__ float dpp_add_xor1(float v) {
  const int p = __builtin_amdgcn_update_dpp(0, __builtin_bit_cast(int, v),
                                            0xB1, 0xF, 0xF, true);
  return v + __builtin_bit_cast(float, p);
}
__device__ __forceinline__ float dpp_add_xor2(float v) {
  const int p = __builtin_amdgcn_update_dpp(0, __builtin_bit_cast(int, v),
                                            0x4E, 0xF, 0xF, true);
  return v + __builtin_bit_cast(float, p);
}
__device__ __forceinline__ float swz_add_xor4(float v) {
  const int p = __builtin_amdgcn_ds_swizzle(__builtin_bit_cast(int, v), 0x101F);
  return v + __builtin_bit_cast(float, p);
}

// ---- packed fp32 FMA (VOP3P, gfx90a+): acc = xy.(lo|hi) * w + acc --------
// acc.lo += x*w.lo ; acc.hi += x*w.hi   where x = xy.lo
__device__ __forceinline__ void pk_fma_lo(v2f& acc, v2f xy, v2f w) {
  asm volatile("v_pk_fma_f32 %0, %1, %2, %0 op_sel:[0,0,0] op_sel_hi:[0,1,1]"
               : "+v"(acc) : "v"(xy), "v"(w));
}
// same with x = xy.hi
__device__ __forceinline__ void pk_fma_hi(v2f& acc, v2f xy, v2f w) {
  asm volatile("v_pk_fma_f32 %0, %1, %2, %0 op_sel:[1,0,0] op_sel_hi:[1,1,1]"
               : "+v"(acc) : "v"(xy), "v"(w));
}
// plain packed: acc.lo += a.lo*b.lo ; acc.hi += a.hi*b.hi
__device__ __forceinline__ void pk_fma_pk(v2f& acc, v2f a, v2f b) {
  asm volatile("v_pk_fma_f32 %0, %1, %2, %0"
               : "+v"(acc) : "v"(a), "v"(b));
}

// ============ r4 structure, DOT converted to packed fp32 FMA ===============
template<int DIN, int H, int NSu, bool CONST_X, bool WRITE_SEQ, bool WRITE_LAST,
         bool FUSE_DENSE>
__global__ void __launch_bounds__(512, 2)
lstm_unit(const float* __restrict__ xin, const float* __restrict__ Wk,
          const float* __restrict__ Wr, const float* __restrict__ bias,
          float* __restrict__ seq_out, float* __restrict__ last_out,
          const float* __restrict__ Wout, const float* __restrict__ boutp,
          float* __restrict__ dense_out)
{
  constexpr int NTH  = 512;
  static_assert(H * NSu == NTH, "block = H*NSu = 512");
  constexpr int KTOT = DIN + H;
  constexpr int SL   = KTOT / NSu;
  constexpr int C4H  = 4 * H;
  constexpr int XH   = DIN + H;
  constexpr int NW   = NTH / 64;
  constexpr int UPW  = 64 / NSu;
  constexpr int DK   = FUSE_DENSE ? (H / NW) : 4;
  static_assert(SL * NSu == KTOT && (SL % 4) == 0, "slice float4-able");
  static_assert(NSu == 4 || NSu == 8, "butterfly depth");

  const int tid = (int)threadIdx.x;
  const int b   = (int)blockIdx.x;
  const int l   = tid & 63;
  const int wv  = tid >> 6;
  const int sl  = l & (NSu - 1);
  const int u   = wv * UPW + (l / NSu);

  __shared__ __align__(16) float xh0[XH], xh1[XH];
  __shared__ __align__(16) float dp[2][FUSE_DENSE ? NW * 64 : 4];

  // weights as packed gate-pairs: wIF[i]=(w_i,w_f), wGO[i]=(w_g,w_o)
  v2f wIF[SL], wGO[SL];
  #pragma unroll
  for (int i = 0; i < SL; ++i) {
    const int k = sl * SL + i;
    const float* col = (k < DIN) ? &Wk[(size_t)k * C4H] : &Wr[(size_t)(k - DIN) * C4H];
    wIF[i] = v2f{col[u],         col[H + u]};
    wGO[i] = v2f{col[2 * H + u], col[3 * H + u]};
  }
  const float bi_ = bias[u], bf_ = bias[H + u], bg_ = bias[2 * H + u], bo_ = bias[3 * H + u];

  v2f woutP[FUSE_DENSE ? DK / 2 : 1];
  float boutr = 0.f;
  if constexpr (FUSE_DENSE) {
    #pragma unroll
    for (int j = 0; j < DK / 2; ++j)
      woutP[j] = v2f{Wout[(size_t)(DK * wv + 2 * j) * 64 + l],
                     Wout[(size_t)(DK * wv + 2 * j + 1) * 64 + l]};
    boutr = boutp[l];
  }

  if (tid < H) xh0[DIN + tid] = 0.f;
  if (tid < DIN / 4) {
    const float4 v = *(const float4*)&xin[(CONST_X ? (size_t)b * DIN
                                                   : (size_t)b * TT * DIN) + 4 * tid];
    *((float4*)xh0 + tid) = v;
    if (CONST_X) *((float4*)xh1 + tid) = v;
  }
  BARRIER();

  float cst = 0.f;
  constexpr int TEND = FUSE_DENSE ? TT + 2 : TT;

  for (int t = 0; t < TEND; ++t) {
    float* xc = (t & 1) ? xh1 : xh0;
    float* xn = (t & 1) ? xh0 : xh1;

    float4 xr;
    const bool do_stage = (!CONST_X) && (tid < DIN / 4) && (t + 1 < TT);
    if (do_stage) xr = *(const float4*)&xin[((size_t)b * TT + (t + 1)) * DIN + 4 * tid];

    if (t < TT) {
      const float4* xv = (const float4*)(xc + sl * SL);
      // 4 packed accumulators -> 4 independent dep chains (24 deep at SL=48)
      v2f aIF0 = {0.f, 0.f}, aIF1 = {0.f, 0.f};
      v2f aGO0 = {0.f, 0.f}, aGO1 = {0.f, 0.f};
      #pragma unroll
      for (int j = 0; j < SL / 4; ++j) {
        const float4 v = xv[j];
        const v2f p01 = {v.x, v.y};
        const v2f p23 = {v.z, v.w};
        pk_fma_lo(aIF0, p01, wIF[4 * j + 0]);  pk_fma_lo(aGO0, p01, wGO[4 * j + 0]);
        pk_fma_hi(aIF1, p01, wIF[4 * j + 1]);  pk_fma_hi(aGO1, p01, wGO[4 * j + 1]);
        pk_fma_lo(aIF0, p23, wIF[4 * j + 2]);  pk_fma_lo(aGO0, p23, wGO[4 * j + 2]);
        pk_fma_hi(aIF1, p23, wIF[4 * j + 3]);  pk_fma_hi(aGO1, p23, wGO[4 * j + 3]);
      }
      float ai = aIF0.x + aIF1.x, af = aIF0.y + aIF1.y;
      float ag = aGO0.x + aGO1.x, ao = aGO0.y + aGO1.y;

      ai = dpp_add_xor1(ai); af = dpp_add_xor1(af);
      ag = dpp_add_xor1(ag); ao = dpp_add_xor1(ao);
      ai = dpp_add_xor2(ai); af = dpp_add_xor2(af);
      ag = dpp_add_xor2(ag); ao = dpp_add_xor2(ao);
      if constexpr (NSu == 8) {
        ai = swz_add_xor4(ai); af = swz_add_xor4(af);
        ag = swz_add_xor4(ag); ao = swz_add_xor4(ao);
      }
      const float gi = sigmoid_fast(ai + bi_);
      const float gf = sigmoid_fast(af + bf_);
      const float go = sigmoid_fast(ao + bo_);
      const float gg = fmaxf(ag + bg_, 0.f);       // activation = relu
      cst = fmaf(gf, cst, gi * gg);                // c = f*c + i*g
      const float h = go * fmaxf(cst, 0.f);        // h = o * relu(c)
      if (sl == 0) {
        xn[DIN + u] = h;
        if constexpr (WRITE_SEQ)  seq_out[((size_t)b * TT + t) * H + u] = h;
        if constexpr (WRITE_LAST) { if (t == TT - 1) last_out[(size_t)b * H + u] = h; }
      }
    }
    if (do_stage) *((float4*)xn + tid) = xr;

    if constexpr (FUSE_DENSE) {
      if (t >= 1 && t <= TT) {
        const float* hsrc = xc + DIN + DK * wv;
        v2f aD0 = {0.f, 0.f}, aD1 = {0.f, 0.f};
        #pragma unroll
        for (int j = 0; j < DK; j += 4) {
          const float4 hv = *(const float4*)(hsrc + j);
          pk_fma_pk(aD0, v2f{hv.x, hv.y}, woutP[j / 2]);
          pk_fma_pk(aD1, v2f{hv.z, hv.w}, woutP[j / 2 + 1]);
        }
        dp[(t - 1) & 1][wv * 64 + l] = (aD0.x + aD0.y) + (aD1.x + aD1.y);
      }
      if (t >= 2 && wv == NW - 1) {
        const float* dq = dp[t & 1];
        float o = boutr;
        #pragma unroll
        for (int j = 0; j < NW; ++j) o += dq[j * 64 + l];
        dense_out[((size_t)b * TT + (t - 2)) * 64 + l] = o;
      }
    }
    if (t < TEND - 1) BARRIER();
  }
}

extern "C" void kernel_launch(void* const* d_in, const int* in_sizes, int n_in,
                              void* d_out, int out_size, void* d_ws, size_t ws_size,
                              hipStream_t stream) {
  const float* x    = (const float*)d_in[0];
  const float* Wk1  = (const float*)d_in[1];
  const float* Wr1  = (const float*)d_in[2];
  const float* b1   = (const float*)d_in[3];
  const float* Wk2  = (const float*)d_in[4];
  const float* Wr2  = (const float*)d_in[5];
  const float* b2   = (const float*)d_in[6];
  const float* Wd1k = (const float*)d_in[7];
  const float* Wd1r = (const float*)d_in[8];
  const float* bd1  = (const float*)d_in[9];
  const float* Wd2k = (const float*)d_in[10];
  const float* Wd2r = (const float*)d_in[11];
  const float* bd2  = (const float*)d_in[12];
  const float* Wout = (const float*)d_in[13];
  const float* bout = (const float*)d_in[14];
  float* out = (float*)d_out;

  // ws: h1 [B,T,128] (64 MB; d1 [B,T,64] overlays it after enc2), z [B,64]
  const size_t h1_elems = (size_t)BB * TT * 128;
  if (ws_size < (h1_elems + (size_t)BB * 64) * sizeof(float)) return;
  float* h1 = (float*)d_ws;
  float* z  = h1 + h1_elems;
  float* d1 = h1;  // h1 dead after enc2

  // encoder 1: 64 -> 128, seq out           (NSu=4, SL=48, 96 pk_fma/step)
  lstm_unit<64, 128, 4, false, true,  false, false><<<BB, 512, 0, stream>>>(
      x,  Wk1,  Wr1,  b1,  h1,      nullptr, nullptr, nullptr, nullptr);
  // encoder 2: 128 -> 64, last state only   (NSu=8, SL=24, 48 pk_fma/step)
  lstm_unit<128, 64, 8, false, false, true,  false><<<BB, 512, 0, stream>>>(
      h1, Wk2,  Wr2,  b2,  nullptr, z,       nullptr, nullptr, nullptr);
  // decoder 1: const z (RepeatVector) -> 64 (NSu=8, SL=16, 32 pk_fma/step)
  lstm_unit<64,  64, 8, true,  true,  false, false><<<BB, 512, 0, stream>>>(
      z,  Wd1k, Wd1r, bd1, d1,      nullptr, nullptr, nullptr, nullptr);
  // decoder 2: 64 -> 128 + fused Dense      (NSu=4, SL=48, 96+8 pk_fma/step)
  lstm_unit<64, 128, 4, false, false, false, true ><<<BB, 512, 0, stream>>>(
      d1, Wd2k, Wd2r, bd2, nullptr, nullptr, Wout,   bout,    out);
}

// Round 14
// 1426.765 us; speedup vs baseline: 1.1422x; 1.1422x over previous
//
#include <hip/hip_runtime.h>

static constexpr int TT = 512;   // sequence length
static constexpr int BB = 256;   // batch

// LDS-only barrier: no vmcnt(0) drain, so global loads stay in flight across
// it (T4/T14 pattern). lgkmcnt(0) makes prior LDS writes visible.
#define BARRIER() do { \
    asm volatile("s_waitcnt lgkmcnt(0)" ::: "memory"); \
    __builtin_amdgcn_s_barrier(); \
    asm volatile("" ::: "memory"); \
  } while (0)

__device__ __forceinline__ float sigmoid_fast(float v) {
  const float e = __builtin_amdgcn_exp2f(v * -1.44269504088896340736f);
  return __builtin_amdgcn_rcpf(1.0f + e);
}
__device__ __forceinline__ float dpp_add_xor1(float v) {
  const int p = __builtin_amdgcn_update_dpp(0, __builtin_bit_cast(int, v),
                                            0xB1, 0xF, 0xF, true);
  return v + __builtin_bit_cast(float, p);
}
__device__ __forceinline__ float dpp_add_xor2(float v) {
  const int p = __builtin_amdgcn_update_dpp(0, __builtin_bit_cast(int, v),
                                            0x4E, 0xF, 0xF, true);
  return v + __builtin_bit_cast(float, p);
}
__device__ __forceinline__ float swz_add_xor4(float v) {
  const int p = __builtin_amdgcn_ds_swizzle(__builtin_bit_cast(int, v), 0x101F);
  return v + __builtin_bit_cast(float, p);
}

// =====================================================================
// Verified-optimal LSTM layer kernel (r4/r12 structure, 1416 us total).
// One workgroup (512 thr = 8 waves, 2/SIMD) per batch row, persistent
// over T, ONE lgkmcnt-only barrier per step. Thread (u, sl) computes all
// 4 gate partial dots for unit u over k-slice sl (weights in registers);
// slices sit in adjacent lanes -> DPP/swizzle butterfly reduction; gates
// computed redundantly by all lanes (no divergence); lane sl==0 writes h.
// CONST_X: RepeatVector input staged once into both ping-pong buffers.
// FUSE_DENSE: TimeDistributed Dense as a 2-step-behind pipeline (partial
// per wave from LDS h + register Wout; reduce by last wave).
// Known-dead levers (measured, do not retry): register-allocation hints
// (3 variants null, VGPR_Count pinned at 128+AGPR); pk_fma (r13: halves
// VALU issue but +13% time -> latency-floor, not issue-bound); producer/
// consumer layer fusion (r6/r7/r11: all slower than this split).
// =====================================================================
template<int DIN, int H, int NSu, bool CONST_X, bool WRITE_SEQ, bool WRITE_LAST,
         bool FUSE_DENSE>
__global__ void __launch_bounds__(512, 2)
lstm_unit(const float* __restrict__ xin, const float* __restrict__ Wk,
          const float* __restrict__ Wr, const float* __restrict__ bias,
          float* __restrict__ seq_out, float* __restrict__ last_out,
          const float* __restrict__ Wout, const float* __restrict__ boutp,
          float* __restrict__ dense_out)
{
  constexpr int NTH  = 512;
  static_assert(H * NSu == NTH, "block = H*NSu = 512");
  constexpr int KTOT = DIN + H;
  constexpr int SL   = KTOT / NSu;
  constexpr int C4H  = 4 * H;
  constexpr int XH   = DIN + H;
  constexpr int NW   = NTH / 64;
  constexpr int UPW  = 64 / NSu;
  constexpr int DK   = FUSE_DENSE ? (H / NW) : 4;
  static_assert(SL * NSu == KTOT && (SL % 4) == 0, "slice float4-able");
  static_assert(NSu == 4 || NSu == 8, "butterfly depth");

  const int tid = (int)threadIdx.x;
  const int b   = (int)blockIdx.x;
  const int l   = tid & 63;
  const int wv  = tid >> 6;
  const int sl  = l & (NSu - 1);
  const int u   = wv * UPW + (l / NSu);

  __shared__ __align__(16) float xh0[XH], xh1[XH];
  __shared__ __align__(16) float dp[2][FUSE_DENSE ? NW * 64 : 4];

  float w[SL * 4];
  #pragma unroll
  for (int i = 0; i < SL; ++i) {
    const int k = sl * SL + i;
    const float* col = (k < DIN) ? &Wk[(size_t)k * C4H] : &Wr[(size_t)(k - DIN) * C4H];
    #pragma unroll
    for (int g = 0; g < 4; ++g) w[i * 4 + g] = col[g * H + u];
  }
  const float bi_ = bias[u], bf_ = bias[H + u], bg_ = bias[2 * H + u], bo_ = bias[3 * H + u];

  float wout_r[DK];
  float boutr = 0.f;
  if constexpr (FUSE_DENSE) {
    #pragma unroll
    for (int j = 0; j < DK; ++j) wout_r[j] = Wout[(size_t)(DK * wv + j) * 64 + l];
    boutr = boutp[l];
  }

  if (tid < H) xh0[DIN + tid] = 0.f;
  if (tid < DIN / 4) {
    const float4 v = *(const float4*)&xin[(CONST_X ? (size_t)b * DIN
                                                   : (size_t)b * TT * DIN) + 4 * tid];
    *((float4*)xh0 + tid) = v;
    if (CONST_X) *((float4*)xh1 + tid) = v;
  }
  BARRIER();

  float cst = 0.f;
  constexpr int TEND = FUSE_DENSE ? TT + 2 : TT;

  for (int t = 0; t < TEND; ++t) {
    float* xc = (t & 1) ? xh1 : xh0;
    float* xn = (t & 1) ? xh0 : xh1;

    float4 xr;
    const bool do_stage = (!CONST_X) && (tid < DIN / 4) && (t + 1 < TT);
    if (do_stage) xr = *(const float4*)&xin[((size_t)b * TT + (t + 1)) * DIN + 4 * tid];

    if (t < TT) {
      const float4* xv = (const float4*)(xc + sl * SL);
      float ai = 0.f, af = 0.f, ag = 0.f, ao = 0.f;
      #pragma unroll
      for (int j = 0; j < SL / 4; ++j) {
        const float4 v = xv[j];
        const float* wj = &w[16 * j];
        ai = fmaf(v.x, wj[0],  ai);  af = fmaf(v.x, wj[1],  af);
        ag = fmaf(v.x, wj[2],  ag);  ao = fmaf(v.x, wj[3],  ao);
        ai = fmaf(v.y, wj[4],  ai);  af = fmaf(v.y, wj[5],  af);
        ag = fmaf(v.y, wj[6],  ag);  ao = fmaf(v.y, wj[7],  ao);
        ai = fmaf(v.z, wj[8],  ai);  af = fmaf(v.z, wj[9],  af);
        ag = fmaf(v.z, wj[10], ag);  ao = fmaf(v.z, wj[11], ao);
        ai = fmaf(v.w, wj[12], ai);  af = fmaf(v.w, wj[13], af);
        ag = fmaf(v.w, wj[14], ag);  ao = fmaf(v.w, wj[15], ao);
      }
      ai = dpp_add_xor1(ai); af = dpp_add_xor1(af);
      ag = dpp_add_xor1(ag); ao = dpp_add_xor1(ao);
      ai = dpp_add_xor2(ai); af = dpp_add_xor2(af);
      ag = dpp_add_xor2(ag); ao = dpp_add_xor2(ao);
      if constexpr (NSu == 8) {
        ai = swz_add_xor4(ai); af = swz_add_xor4(af);
        ag = swz_add_xor4(ag); ao = swz_add_xor4(ao);
      }
      const float gi = sigmoid_fast(ai + bi_);
      const float gf = sigmoid_fast(af + bf_);
      const float go = sigmoid_fast(ao + bo_);
      const float gg = fmaxf(ag + bg_, 0.f);       // activation = relu
      cst = fmaf(gf, cst, gi * gg);                // c = f*c + i*g
      const float h = go * fmaxf(cst, 0.f);        // h = o * relu(c)
      if (sl == 0) {
        xn[DIN + u] = h;
        if constexpr (WRITE_SEQ)  seq_out[((size_t)b * TT + t) * H + u] = h;
        if constexpr (WRITE_LAST) { if (t == TT - 1) last_out[(size_t)b * H + u] = h; }
      }
    }
    if (do_stage) *((float4*)xn + tid) = xr;

    if constexpr (FUSE_DENSE) {
      if (t >= 1 && t <= TT) {
        const float* hsrc = xc + DIN + DK * wv;
        float a = 0.f;
        #pragma unroll
        for (int j = 0; j < DK; j += 4) {
          const float4 hv = *(const float4*)(hsrc + j);
          a = fmaf(hv.x, wout_r[j + 0], a);
          a = fmaf(hv.y, wout_r[j + 1], a);
          a = fmaf(hv.z, wout_r[j + 2], a);
          a = fmaf(hv.w, wout_r[j + 3], a);
        }
        dp[(t - 1) & 1][wv * 64 + l] = a;
      }
      if (t >= 2 && wv == NW - 1) {
        const float* dq = dp[t & 1];
        float o = boutr;
        #pragma unroll
        for (int j = 0; j < NW; ++j) o += dq[j * 64 + l];
        dense_out[((size_t)b * TT + (t - 2)) * 64 + l] = o;
      }
    }
    if (t < TEND - 1) BARRIER();
  }
}

extern "C" void kernel_launch(void* const* d_in, const int* in_sizes, int n_in,
                              void* d_out, int out_size, void* d_ws, size_t ws_size,
                              hipStream_t stream) {
  const float* x    = (const float*)d_in[0];
  const float* Wk1  = (const float*)d_in[1];
  const float* Wr1  = (const float*)d_in[2];
  const float* b1   = (const float*)d_in[3];
  const float* Wk2  = (const float*)d_in[4];
  const float* Wr2  = (const float*)d_in[5];
  const float* b2   = (const float*)d_in[6];
  const float* Wd1k = (const float*)d_in[7];
  const float* Wd1r = (const float*)d_in[8];
  const float* bd1  = (const float*)d_in[9];
  const float* Wd2k = (const float*)d_in[10];
  const float* Wd2r = (const float*)d_in[11];
  const float* bd2  = (const float*)d_in[12];
  const float* Wout = (const float*)d_in[13];
  const float* bout = (const float*)d_in[14];
  float* out = (float*)d_out;

  // ws: h1 [B,T,128] (64 MB; d1 [B,T,64] overlays it after enc2), z [B,64]
  const size_t h1_elems = (size_t)BB * TT * 128;
  if (ws_size < (h1_elems + (size_t)BB * 64) * sizeof(float)) return;
  float* h1 = (float*)d_ws;
  float* z  = h1 + h1_elems;
  float* d1 = h1;  // h1 dead after enc2

  // encoder 1: 64 -> 128, seq out           (NSu=4, SL=48, w[192])
  lstm_unit<64, 128, 4, false, true,  false, false><<<BB, 512, 0, stream>>>(
      x,  Wk1,  Wr1,  b1,  h1,      nullptr, nullptr, nullptr, nullptr);
  // encoder 2: 128 -> 64, last state only   (NSu=8, SL=24, w[96])
  lstm_unit<128, 64, 8, false, false, true,  false><<<BB, 512, 0, stream>>>(
      h1, Wk2,  Wr2,  b2,  nullptr, z,       nullptr, nullptr, nullptr);
  // decoder 1: const z (RepeatVector) -> 64 (NSu=8, SL=16, w[64])
  lstm_unit<64,  64, 8, true,  true,  false, false><<<BB, 512, 0, stream>>>(
      z,  Wd1k, Wd1r, bd1, d1,      nullptr, nullptr, nullptr, nullptr);
  // decoder 2: 64 -> 128 + fused Dense 128->64 (NSu=4, SL=48, w[192]+wout[16])
  lstm_unit<64, 128, 4, false, false, false, true ><<<BB, 512, 0, stream>>>(
      d1, Wd2k, Wd2r, bd2, nullptr, nullptr, Wout,   bout,    out);
}